// Round 3
// baseline (1571.972 us; speedup 1.0000x reference)
//
#include <hip/hip_runtime.h>
#include <hip/hip_bf16.h>

// AlignmentContrastiveLoss on MI355X.
//   K1 normalize_pack: fp32 L2-normalize, drop CLS/special tokens, cast bf16,
//      zero-padded im' [256][48][1024], s' [256][32][1024] in ws.
//   K2 gemm_scores: bf16 MFMA GEMM (M=96, N=256, K=1024 per block).
//      Staging: buffer_load -> VGPR (explicit k+1 prefetch, loads stay in
//      flight across barriers) -> ds_write_b128 into XOR-swizzled LDS
//      (conflict-free reads AND writes, verified 0 conflicts in R2).
//      Fused masked max-over-regions / sum-over-words epilogue -> scores.
//   K3 loss_part (256 blocks) + K4 loss_final: hardest-negative loss.

typedef __attribute__((ext_vector_type(8))) short bf16x8;
typedef __attribute__((ext_vector_type(4))) float f32x4;

#define NB   256
#define DIM  1024
#define LI   36     // valid image regions after dropping CLS
#define LIP  48     // padded to 3 x 16
#define LS   30     // valid words after dropping first + last two
#define LSP  32     // padded to 2 x 16

static __device__ inline ushort f2bf(float x) {
    union { __hip_bfloat16 h; ushort u; } cvt;
    cvt.h = __float2bfloat16(x);
    return cvt.u;
}

// One wave per output row. Rows 0..256*48-1 -> im', rest -> s'.
__global__ __launch_bounds__(256) void normalize_pack(
    const float* __restrict__ im, const float* __restrict__ sq,
    short* __restrict__ imp, short* __restrict__ sp)
{
    const int gw   = (blockIdx.x * 256 + threadIdx.x) >> 6;
    const int lane = threadIdx.x & 63;
    const int NIM  = NB * LIP;

    const float* src = nullptr;
    short* dst;
    if (gw < NIM) {
        int b = gw / LIP, i = gw - b * LIP;
        dst = imp + (size_t)gw * DIM;
        if (i < LI) src = im + ((size_t)b * 37 + i + 1) * DIM;   // drop CLS region 0
    } else {
        int g2 = gw - NIM;
        int b = g2 / LSP, j = g2 - b * LSP;
        dst = sp + (size_t)g2 * DIM;
        if (j < LS) src = sq + ((size_t)b * 33 + j + 1) * DIM;   // rows 1..30 of 33
    }

    if (src) {
        const float4* s4 = (const float4*)src;
        float4 v[4];
        float ss = 0.f;
        #pragma unroll
        for (int t = 0; t < 4; ++t) {
            float4 x = s4[lane + 64 * t];
            v[t] = x;
            ss += x.x * x.x + x.y * x.y + x.z * x.z + x.w * x.w;
        }
        #pragma unroll
        for (int o = 32; o >= 1; o >>= 1) ss += __shfl_xor(ss, o, 64);
        float scale = 1.0f / fmaxf(sqrtf(ss), 1e-12f);
        ushort4* d4 = (ushort4*)dst;
        #pragma unroll
        for (int t = 0; t < 4; ++t) {
            float4 x = v[t];
            ushort4 o;
            o.x = f2bf(x.x * scale);
            o.y = f2bf(x.y * scale);
            o.z = f2bf(x.z * scale);
            o.w = f2bf(x.w * scale);
            d4[lane + 64 * t] = o;
        }
    } else {
        uint4 z = {0u, 0u, 0u, 0u};
        uint4* d4 = (uint4*)dst;   // 1024 bf16 = 128 uint4
        d4[lane] = z;
        d4[lane + 64] = z;
    }
}

// Block: 256 threads = 4 waves. blockIdx.x -> image pair (b0=2*x),
// blockIdx.y -> 8 sentences (c0=8*y). Wave w owns N-tiles 4w..4w+3; its 4
// score cells are wave-private (no atomics).
// LDS layout: unpadded 128 B rows (64 bf16). 16 B chunk slot (row, c) holds
// global chunk (row, c ^ (row&7)): global reads stay straight/coalesced,
// the swizzle is applied on the ds_write slot. Both the write pattern
// (8 lanes cover one permuted 128 B row-segment) and the fragment-read
// pattern (2 lanes/bank-group) are conflict-free (R2 measured 0).
__global__ __launch_bounds__(256) void gemm_scores(
    const short* __restrict__ imp, const short* __restrict__ sp,
    const int* __restrict__ im_len, const int* __restrict__ s_len,
    float* __restrict__ scores)
{
    __shared__ short As[96 * 64];    // 12 KB
    __shared__ short Bs[256 * 64];   // 32 KB

    const int tid  = threadIdx.x;
    const int wave = tid >> 6;
    const int lane = tid & 63;
    const int q    = lane >> 4;
    const int l15  = lane & 15;
    const int b0   = blockIdx.x * 2;
    const int c0   = blockIdx.y * 8;

    f32x4 acc[6][4];
    #pragma unroll
    for (int mt = 0; mt < 6; ++mt)
        #pragma unroll
        for (int t = 0; t < 4; ++t)
            acc[mt][t] = (f32x4){0.f, 0.f, 0.f, 0.f};

    // Per-thread staging chunk ids. Global read: straight (row, col).
    // LDS write slot: (row, col ^ (row&7)).
    const char* gAb = (const char*)imp + (size_t)b0 * LIP * 2048;
    const char* gBb = (const char*)sp  + (size_t)c0 * LSP * 2048;
    const char* aSrc[3]; short* aDst[3];
    #pragma unroll
    for (int it = 0; it < 3; ++it) {
        int cid = it * 256 + tid, row = cid >> 3, col = cid & 7;
        aSrc[it] = gAb + row * 2048 + col * 16;
        aDst[it] = &As[row * 64 + (col ^ (row & 7)) * 8];
    }
    const char* bSrc[8]; short* bDst[8];
    #pragma unroll
    for (int it = 0; it < 8; ++it) {
        int cid = it * 256 + tid, row = cid >> 3, col = cid & 7;
        bSrc[it] = gBb + row * 2048 + col * 16;
        bDst[it] = &Bs[row * 64 + (col ^ (row & 7)) * 8];
    }

    uint4 aCur[3], bCur[8], aNxt[3], bNxt[8];
    #pragma unroll
    for (int it = 0; it < 3; ++it) aCur[it] = *(const uint4*)aSrc[it];
    #pragma unroll
    for (int it = 0; it < 8; ++it) bCur[it] = *(const uint4*)bSrc[it];

    for (int k0 = 0; k0 < 16; ++k0) {
        if (k0) __syncthreads();           // previous iter's readers done
        #pragma unroll
        for (int it = 0; it < 3; ++it) *(uint4*)aDst[it] = aCur[it];
        #pragma unroll
        for (int it = 0; it < 8; ++it) *(uint4*)bDst[it] = bCur[it];
        __syncthreads();                   // tile visible

        if (k0 < 15) {
            const int kb = (k0 + 1) * 128; // 64 bf16 = 128 B along K
            #pragma unroll
            for (int it = 0; it < 3; ++it)
                aNxt[it] = *(const uint4*)(aSrc[it] + kb);
            #pragma unroll
            for (int it = 0; it < 8; ++it)
                bNxt[it] = *(const uint4*)(bSrc[it] + kb);
        }

        #pragma unroll
        for (int g = 0; g < 2; ++g) {
            const int cw = ((g * 4 + q) ^ (l15 & 7)) * 8;  // swizzled chunk col
            bf16x8 af[6], bfr[4];
            #pragma unroll
            for (int mt = 0; mt < 6; ++mt)
                af[mt] = *(const bf16x8*)&As[(mt * 16 + l15) * 64 + cw];
            #pragma unroll
            for (int t = 0; t < 4; ++t)
                bfr[t] = *(const bf16x8*)&Bs[((wave * 4 + t) * 16 + l15) * 64 + cw];
            #pragma unroll
            for (int mt = 0; mt < 6; ++mt)
                #pragma unroll
                for (int t = 0; t < 4; ++t)
                    acc[mt][t] = __builtin_amdgcn_mfma_f32_16x16x32_bf16(
                        af[mt], bfr[t], acc[mt][t], 0, 0, 0);
        }

        #pragma unroll
        for (int it = 0; it < 3; ++it) aCur[it] = aNxt[it];
        #pragma unroll
        for (int it = 0; it < 8; ++it) bCur[it] = bNxt[it];
    }

    // Fused epilogue. C/D layout: lane holds col = lane&15, row = (lane>>4)*4 + r.
    const int iml0 = im_len[b0] - 1;       // in [9, 36]
    const int iml1 = im_len[b0 + 1] - 1;

    float sc[2][2] = {{0.f, 0.f}, {0.f, 0.f}};
    #pragma unroll
    for (int t = 0; t < 4; ++t) {
        const int nt = wave * 4 + t;
        const int c  = c0 + (nt >> 1);
        const int sl = s_len[c] - 3;                 // valid words, in [5, 30]
        const int jj = (nt & 1) * 16 + l15;          // word index within sentence
        const bool jv = (jj < sl);
        #pragma unroll
        for (int bb = 0; bb < 2; ++bb) {
            const int il = bb ? iml1 : iml0;
            float m = -3.4e38f;
            #pragma unroll
            for (int mt3 = 0; mt3 < 3; ++mt3) {
                #pragma unroll
                for (int r = 0; r < 4; ++r) {
                    int i = mt3 * 16 + q * 4 + r;    // global region index
                    float v = acc[bb * 3 + mt3][t][r];
                    if (i < il) m = fmaxf(m, v);     // pads & masked rows excluded
                }
            }
            m = fmaxf(m, __shfl_xor(m, 16, 64));
            m = fmaxf(m, __shfl_xor(m, 32, 64));
            // reference: masked entries are 0 and join the max iff il < 36
            if (il < LI) m = fmaxf(m, 0.f);
            float v = (q == 0 && jv) ? m : 0.f;      // count each column once
            #pragma unroll
            for (int off = 32; off >= 1; off >>= 1) v += __shfl_xor(v, off, 64);
            sc[bb][t >> 1] += v;
        }
    }
    if (lane == 0) {
        #pragma unroll
        for (int bb = 0; bb < 2; ++bb)
            #pragma unroll
            for (int h = 0; h < 2; ++h)
                scores[(b0 + bb) * NB + c0 + wave * 2 + h] = sc[bb][h];
    }
}

// Block t: cost_s[t] = max_{c!=t} relu(M + s[t][c] - s[t][t]),
//          cost_im[t] = max_{b!=t} relu(M + s[b][t] - s[t][t]).
__global__ __launch_bounds__(256) void loss_part(
    const float* __restrict__ sc, float* __restrict__ part)
{
    const int t = blockIdx.x, k = threadIdx.x;
    const float dt = sc[t * (NB + 1)];
    float rv = 0.f, cv = 0.f;
    if (k != t) {
        rv = fmaxf(0.2f + sc[t * NB + k] - dt, 0.f);
        cv = fmaxf(0.2f + sc[k * NB + t] - dt, 0.f);
    }
    #pragma unroll
    for (int o = 32; o >= 1; o >>= 1) {
        rv = fmaxf(rv, __shfl_xor(rv, o, 64));
        cv = fmaxf(cv, __shfl_xor(cv, o, 64));
    }
    __shared__ float rr[4], cc[4];
    if ((k & 63) == 0) { rr[k >> 6] = rv; cc[k >> 6] = cv; }
    __syncthreads();
    if (k == 0) {
        float rm = fmaxf(fmaxf(rr[0], rr[1]), fmaxf(rr[2], rr[3]));
        float cm = fmaxf(fmaxf(cc[0], cc[1]), fmaxf(cc[2], cc[3]));
        part[t] = rm + cm;
    }
}

__global__ __launch_bounds__(256) void loss_final(
    const float* __restrict__ part, float* __restrict__ out)
{
    float v = part[threadIdx.x];
    __shared__ float red[4];
    #pragma unroll
    for (int o = 32; o >= 1; o >>= 1) v += __shfl_xor(v, o, 64);
    if ((threadIdx.x & 63) == 0) red[threadIdx.x >> 6] = v;
    __syncthreads();
    if (threadIdx.x == 0) out[0] = red[0] + red[1] + red[2] + red[3];
}

extern "C" void kernel_launch(void* const* d_in, const int* in_sizes, int n_in,
                              void* d_out, int out_size, void* d_ws, size_t ws_size,
                              hipStream_t stream) {
    const float* im_set = (const float*)d_in[0];
    const float* s_seq  = (const float*)d_in[1];
    const int*   im_len = (const int*)d_in[2];
    const int*   s_len  = (const int*)d_in[3];
    float* out = (float*)d_out;

    char* ws = (char*)d_ws;
    const size_t imp_bytes = (size_t)NB * LIP * DIM * 2;   // 25.2 MB
    const size_t sp_bytes  = (size_t)NB * LSP * DIM * 2;   // 16.8 MB
    short* imp    = (short*)ws;
    short* sp     = (short*)(ws + imp_bytes);
    float* scores = (float*)(ws + imp_bytes + sp_bytes);   // 256 KB
    float* part   = scores + NB * NB;                      // 1 KB

    normalize_pack<<<5120, 256, 0, stream>>>(im_set, s_seq, imp, sp);

    dim3 grid(NB / 2, NB / 8);
    gemm_scores<<<grid, 256, 0, stream>>>(imp, sp, im_len, s_len, scores);

    loss_part<<<NB, 256, 0, stream>>>(scores, part);
    loss_final<<<1, 256, 0, stream>>>(part, out);
}

// Round 5
// 443.430 us; speedup vs baseline: 3.5450x; 3.5450x over previous
//
#include <hip/hip_runtime.h>
#include <hip/hip_bf16.h>

// AlignmentContrastiveLoss on MI355X.
//   K1 norm_pack: fp32 L2-normalize, drop CLS/special tokens, cast bf16 and
//      write directly in MFMA-fragment tile order:
//        apack[img][kc][mt][lane][j]  (1 KB per (img,kc,mt) chunk)
//        bpack[sent][kc][nt][lane][j]
//      where element = X[row = t*16 + (lane&15)][k = kc*32 + (lane>>4)*8 + j],
//      zero for pad rows. This makes every GEMM fragment load one contiguous
//      1 KB coalesced burst.
//   K2 gemm_scores: NO LDS, NO barriers — pure global(L1/L2-hot)->MFMA K-loop
//      with ping-pong register prefetch. Wave tile 6Mx4N (acc 96 regs; R3
//      taught us the spill cliff, so buffering is capped at 20 fragments).
//      Fused masked max-over-regions / sum-over-words epilogue -> scores.
//   K3 loss_part (256 blocks) + K4 loss_final: hardest-negative loss.

typedef __attribute__((ext_vector_type(8))) short bf16x8;
typedef __attribute__((ext_vector_type(4))) float f32x4;

#define NB   256
#define DIM  1024
#define LI   36     // valid image regions after dropping CLS
#define LS   30     // valid words after dropping first + last two

// packed strides (bytes)
#define A_IMG_B   98304    // 32 kc * 3 tiles * 1024 B
#define B_SNT_B   65536    // 32 kc * 2 tiles * 1024 B

static __device__ inline ushort f2bf(float x) {
    union { __hip_bfloat16 h; ushort u; } cvt;
    cvt.h = __float2bfloat16(x);
    return cvt.u;
}

// 512 blocks: blk<256 -> image idx, else sentence idx. Phase 1: row norms.
// Phase 2: write fragment-ordered bf16 chunks (coalesced 16 B/lane bursts).
__global__ __launch_bounds__(256) void norm_pack(
    const float* __restrict__ im, const float* __restrict__ sq,
    short* __restrict__ apack, short* __restrict__ bpack)
{
    __shared__ float scale[48];
    const int blk  = blockIdx.x;
    const bool isIm = blk < NB;
    const int idx  = isIm ? blk : blk - NB;
    const float* src = isIm ? im + (size_t)idx * 37 * DIM + DIM    // rows 1..36
                            : sq + (size_t)idx * 33 * DIM + DIM;   // rows 1..30
    const int nrows = isIm ? LI : LS;
    const int wave = threadIdx.x >> 6, lane = threadIdx.x & 63;
    const int q = lane >> 4, l15 = lane & 15;

    for (int r = wave; r < nrows; r += 4) {
        const float4* s4 = (const float4*)(src + r * DIM);
        float ss = 0.f;
        #pragma unroll
        for (int t = 0; t < 4; ++t) {
            float4 x = s4[lane + 64 * t];
            ss += x.x * x.x + x.y * x.y + x.z * x.z + x.w * x.w;
        }
        #pragma unroll
        for (int o = 32; o >= 1; o >>= 1) ss += __shfl_xor(ss, o, 64);
        if (lane == 0) scale[r] = 1.0f / fmaxf(sqrtf(ss), 1e-12f);
    }
    __syncthreads();

    const int ntiles = isIm ? 3 : 2;
    short* dst = isIm ? apack + (size_t)idx * (A_IMG_B / 2)
                      : bpack + (size_t)idx * (B_SNT_B / 2);
    const int nch = 32 * ntiles;
    for (int ch = wave; ch < nch; ch += 4) {
        const int kc = ch / ntiles, mt = ch - kc * ntiles;
        const int row = mt * 16 + l15;
        const int col = kc * 32 + q * 8;
        union { ushort u[8]; uint4 v; } out;
        out.v = (uint4){0u, 0u, 0u, 0u};
        if (row < nrows) {
            const float* p = src + row * DIM + col;
            float4 x0 = *(const float4*)p;
            float4 x1 = *(const float4*)(p + 4);
            float s = scale[row];
            out.u[0] = f2bf(x0.x * s); out.u[1] = f2bf(x0.y * s);
            out.u[2] = f2bf(x0.z * s); out.u[3] = f2bf(x0.w * s);
            out.u[4] = f2bf(x1.x * s); out.u[5] = f2bf(x1.y * s);
            out.u[6] = f2bf(x1.z * s); out.u[7] = f2bf(x1.w * s);
        }
        *(uint4*)(dst + (size_t)ch * 512 + lane * 8) = out.v;
    }
}

// Block = 4 waves. blockIdx.x -> image pair (b0=2x), blockIdx.y -> 8
// sentences (c0=8y). Wave w owns sentences c0+2w, c0+2w+1 (4 N-tiles);
// all 6 M-tiles. K-loop: 32 chunks of K=32, ping-pong register prefetch,
// no LDS, no __syncthreads. Final-iter over-read (<4 KB) lands inside ws.
__global__ __launch_bounds__(256) void gemm_scores(
    const short* __restrict__ apack, const short* __restrict__ bpack,
    const int* __restrict__ im_len, const int* __restrict__ s_len,
    float* __restrict__ scores)
{
    const int tid  = threadIdx.x;
    const int wave = tid >> 6;
    const int lane = tid & 63;
    const int q    = lane >> 4;
    const int l15  = lane & 15;
    const int b0   = blockIdx.x * 2;
    const int c0   = blockIdx.y * 8;

    const char* aB = (const char*)apack + (size_t)b0 * A_IMG_B + lane * 16;
    const char* bB = (const char*)bpack + (size_t)(c0 + 2 * wave) * B_SNT_B + lane * 16;

    const char* ap[6];
    const char* bp[4];
    #pragma unroll
    for (int mt = 0; mt < 3; ++mt) {
        ap[mt]     = aB + mt * 1024;
        ap[mt + 3] = aB + A_IMG_B + mt * 1024;
    }
    #pragma unroll
    for (int t = 0; t < 4; ++t)
        bp[t] = bB + (t >> 1) * B_SNT_B + (t & 1) * 1024;

    f32x4 acc[6][4];
    #pragma unroll
    for (int mt = 0; mt < 6; ++mt)
        #pragma unroll
        for (int t = 0; t < 4; ++t)
            acc[mt][t] = (f32x4){0.f, 0.f, 0.f, 0.f};

    bf16x8 A0[6], B0[4], A1[6], B1[4];
    #pragma unroll
    for (int mt = 0; mt < 6; ++mt) A0[mt] = *(const bf16x8*)ap[mt];
    #pragma unroll
    for (int t = 0; t < 4; ++t)    B0[t]  = *(const bf16x8*)bp[t];

    for (int it = 0; it < 16; ++it) {
        // prefetch odd chunk (2it+1)
        #pragma unroll
        for (int mt = 0; mt < 6; ++mt) A1[mt] = *(const bf16x8*)(ap[mt] + 3072);
        #pragma unroll
        for (int t = 0; t < 4; ++t)    B1[t]  = *(const bf16x8*)(bp[t] + 2048);
        // compute even chunk
        #pragma unroll
        for (int mt = 0; mt < 6; ++mt)
            #pragma unroll
            for (int t = 0; t < 4; ++t)
                acc[mt][t] = __builtin_amdgcn_mfma_f32_16x16x32_bf16(
                    A0[mt], B0[t], acc[mt][t], 0, 0, 0);
        // advance to next even chunk (2it+2) and prefetch it
        #pragma unroll
        for (int mt = 0; mt < 6; ++mt) ap[mt] += 6144;
        #pragma unroll
        for (int t = 0; t < 4; ++t)    bp[t]  += 4096;
        #pragma unroll
        for (int mt = 0; mt < 6; ++mt) A0[mt] = *(const bf16x8*)ap[mt];
        #pragma unroll
        for (int t = 0; t < 4; ++t)    B0[t]  = *(const bf16x8*)bp[t];
        // compute odd chunk
        #pragma unroll
        for (int mt = 0; mt < 6; ++mt)
            #pragma unroll
            for (int t = 0; t < 4; ++t)
                acc[mt][t] = __builtin_amdgcn_mfma_f32_16x16x32_bf16(
                    A1[mt], B1[t], acc[mt][t], 0, 0, 0);
    }

    // Fused epilogue. C/D layout: lane holds col = lane&15, row = (lane>>4)*4 + r.
    const int iml0 = im_len[b0] - 1;       // in [9, 36]
    const int iml1 = im_len[b0 + 1] - 1;

    float sc[2][2] = {{0.f, 0.f}, {0.f, 0.f}};
    #pragma unroll
    for (int t = 0; t < 4; ++t) {
        const int nt = wave * 4 + t;
        const int c  = c0 + (nt >> 1);
        const int sl = s_len[c] - 3;                 // valid words, in [5, 30]
        const int jj = (nt & 1) * 16 + l15;          // word index within sentence
        const bool jv = (jj < sl);
        #pragma unroll
        for (int bb = 0; bb < 2; ++bb) {
            const int il = bb ? iml1 : iml0;
            float m = -3.4e38f;
            #pragma unroll
            for (int mt3 = 0; mt3 < 3; ++mt3) {
                #pragma unroll
                for (int r = 0; r < 4; ++r) {
                    int i = mt3 * 16 + q * 4 + r;    // global region index
                    float v = acc[bb * 3 + mt3][t][r];
                    if (i < il) m = fmaxf(m, v);     // pads & masked rows excluded
                }
            }
            m = fmaxf(m, __shfl_xor(m, 16, 64));
            m = fmaxf(m, __shfl_xor(m, 32, 64));
            // reference: masked entries are 0 and join the max iff il < 36
            if (il < LI) m = fmaxf(m, 0.f);
            float v = (q == 0 && jv) ? m : 0.f;      // count each column once
            #pragma unroll
            for (int off = 32; off >= 1; off >>= 1) v += __shfl_xor(v, off, 64);
            sc[bb][t >> 1] += v;
        }
    }
    if (lane == 0) {
        #pragma unroll
        for (int bb = 0; bb < 2; ++bb)
            #pragma unroll
            for (int h = 0; h < 2; ++h)
                scores[(b0 + bb) * NB + c0 + wave * 2 + h] = sc[bb][h];
    }
}

// Block t: cost_s[t] = max_{c!=t} relu(M + s[t][c] - s[t][t]),
//          cost_im[t] = max_{b!=t} relu(M + s[b][t] - s[t][t]).
__global__ __launch_bounds__(256) void loss_part(
    const float* __restrict__ sc, float* __restrict__ part)
{
    const int t = blockIdx.x, k = threadIdx.x;
    const float dt = sc[t * (NB + 1)];
    float rv = 0.f, cv = 0.f;
    if (k != t) {
        rv = fmaxf(0.2f + sc[t * NB + k] - dt, 0.f);
        cv = fmaxf(0.2f + sc[k * NB + t] - dt, 0.f);
    }
    #pragma unroll
    for (int o = 32; o >= 1; o >>= 1) {
        rv = fmaxf(rv, __shfl_xor(rv, o, 64));
        cv = fmaxf(cv, __shfl_xor(cv, o, 64));
    }
    __shared__ float rr[4], cc[4];
    if ((k & 63) == 0) { rr[k >> 6] = rv; cc[k >> 6] = cv; }
    __syncthreads();
    if (k == 0) {
        float rm = fmaxf(fmaxf(rr[0], rr[1]), fmaxf(rr[2], rr[3]));
        float cm = fmaxf(fmaxf(cc[0], cc[1]), fmaxf(cc[2], cc[3]));
        part[t] = rm + cm;
    }
}

__global__ __launch_bounds__(256) void loss_final(
    const float* __restrict__ part, float* __restrict__ out)
{
    float v = part[threadIdx.x];
    __shared__ float red[4];
    #pragma unroll
    for (int o = 32; o >= 1; o >>= 1) v += __shfl_xor(v, o, 64);
    if ((threadIdx.x & 63) == 0) red[threadIdx.x >> 6] = v;
    __syncthreads();
    if (threadIdx.x == 0) out[0] = red[0] + red[1] + red[2] + red[3];
}

extern "C" void kernel_launch(void* const* d_in, const int* in_sizes, int n_in,
                              void* d_out, int out_size, void* d_ws, size_t ws_size,
                              hipStream_t stream) {
    const float* im_set = (const float*)d_in[0];
    const float* s_seq  = (const float*)d_in[1];
    const int*   im_len = (const int*)d_in[2];
    const int*   s_len  = (const int*)d_in[3];
    float* out = (float*)d_out;

    char* ws = (char*)d_ws;
    const size_t apack_bytes = (size_t)NB * A_IMG_B;   // 25.2 MB
    const size_t bpack_bytes = (size_t)NB * B_SNT_B;   // 16.8 MB
    short* apack  = (short*)ws;
    short* bpack  = (short*)(ws + apack_bytes);
    float* scores = (float*)(ws + apack_bytes + bpack_bytes);  // 256 KB
    float* part   = scores + NB * NB;                          // 1 KB
    // (final-iteration dead prefetch over-reads < 4 KB past apack/bpack ends;
    //  both land inside this same ws allocation -> safe)

    norm_pack<<<512, 256, 0, stream>>>(im_set, s_seq, apack, bpack);

    dim3 grid(NB / 2, NB / 8);
    gemm_scores<<<grid, 256, 0, stream>>>(apack, bpack, im_len, s_len, scores);

    loss_part<<<NB, 256, 0, stream>>>(scores, part);
    loss_final<<<1, 256, 0, stream>>>(part, out);
}

// Round 6
// 427.530 us; speedup vs baseline: 3.6769x; 1.0372x over previous
//
#include <hip/hip_runtime.h>
#include <hip/hip_bf16.h>

// AlignmentContrastiveLoss on MI355X.
//   K1 norm_pack: fp32 L2-normalize, drop CLS/special tokens, cast bf16,
//      write in MFMA-fragment tile order via LDS row staging (coalesced in+out):
//        apack[img][kc][mt][lane][8], bpack[snt][kc][nt][lane][8]
//      element = X[row = mt*16+(lane&15)][k = kc*32+(lane>>4)*8 + j], 0 for pads.
//   K2 gemm_scores: hybrid-pipe GEMM (M=96, N=256, K=1024 per block):
//      A (reused 4x) via double-buffered LDS windows of K=64; B (streamed,
//      wave-private) direct global->reg ping-pong from bpack. Raw
//      "s_waitcnt lgkmcnt(0); s_barrier" so global prefetches stay in flight
//      across the barrier (only ds_writes drain). Pipe budget per block:
//      MFMA 14.9k cyc (binding), LDS 960 ops*12=11.5k, L1 704KB < 953KB.
//      Fused masked max-over-regions / sum-over-words epilogue -> scores.
//   K3 loss_part (256 blocks) + K4 loss_final: hardest-negative loss.

typedef __attribute__((ext_vector_type(8))) short bf16x8;
typedef __attribute__((ext_vector_type(4))) float f32x4;

#define NB   256
#define DIM  1024
#define LI   36     // valid image regions after dropping CLS
#define LS   30     // valid words after dropping first + last two

// packed strides (bytes)
#define A_IMG_B   98304    // 32 kc * 3 tiles * 1024 B
#define B_SNT_B   65536    // 32 kc * 2 tiles * 1024 B

#define RBS 1032   // norm_pack LDS row stride in shorts (2064 B: 16B-aligned)

static __device__ inline ushort f2bf(float x) {
    union { __hip_bfloat16 h; ushort u; } cvt;
    cvt.h = __float2bfloat16(x);
    return cvt.u;
}

// 512 blocks: blk<256 -> image, else sentence. Phase 1: coalesced row reads,
// norm, scaled bf16 rows into LDS. Phase 2: fragment-ordered chunks from LDS,
// coalesced 1 KB global writes.
__global__ __launch_bounds__(256) void norm_pack(
    const float* __restrict__ im, const float* __restrict__ sq,
    short* __restrict__ apack, short* __restrict__ bpack)
{
    __shared__ short rb[36 * RBS];   // 74.3 KB
    const int blk  = blockIdx.x;
    const bool isIm = blk < NB;
    const int idx  = isIm ? blk : blk - NB;
    const float* src = isIm ? im + (size_t)idx * 37 * DIM + DIM    // rows 1..36
                            : sq + (size_t)idx * 33 * DIM + DIM;   // rows 1..30
    const int nrows = isIm ? LI : LS;
    const int wave = threadIdx.x >> 6, lane = threadIdx.x & 63;
    const int q = lane >> 4, l15 = lane & 15;

    for (int r = wave; r < nrows; r += 4) {
        const float4* s4 = (const float4*)(src + (size_t)r * DIM);
        float4 v[4];
        float ss = 0.f;
        #pragma unroll
        for (int t = 0; t < 4; ++t) {
            float4 x = s4[lane + 64 * t];
            v[t] = x;
            ss += x.x * x.x + x.y * x.y + x.z * x.z + x.w * x.w;
        }
        #pragma unroll
        for (int o = 32; o >= 1; o >>= 1) ss += __shfl_xor(ss, o, 64);
        float s = 1.0f / fmaxf(sqrtf(ss), 1e-12f);
        #pragma unroll
        for (int t = 0; t < 4; ++t) {
            ushort4 o;
            o.x = f2bf(v[t].x * s); o.y = f2bf(v[t].y * s);
            o.z = f2bf(v[t].z * s); o.w = f2bf(v[t].w * s);
            *(ushort4*)&rb[r * RBS + 4 * lane + 256 * t] = o;
        }
    }
    __syncthreads();

    const int ntiles = isIm ? 3 : 2;
    short* dst = isIm ? apack + (size_t)idx * (A_IMG_B / 2)
                      : bpack + (size_t)idx * (B_SNT_B / 2);
    const int nch = 32 * ntiles;
    for (int ch = wave; ch < nch; ch += 4) {
        const int kc = ch / ntiles, mt = ch - kc * ntiles;
        const int row = mt * 16 + l15;
        const int col = kc * 32 + q * 8;
        uint4 vz = (uint4){0u, 0u, 0u, 0u};
        if (row < nrows) vz = *(const uint4*)&rb[row * RBS + col];
        *(uint4*)(dst + (size_t)ch * 512 + lane * 8) = vz;
    }
}

// Block = 4 waves. blockIdx.x -> image pair (b0=2x), blockIdx.y -> 8
// sentences (c0=8y). Wave w owns sentences c0+2w, c0+2w+1 (4 N-frag cols);
// all 6 M-frag rows (2 img x 3 tiles). acc[f=img*3+mt][t] wave-private.
__global__ __launch_bounds__(256) void gemm_scores(
    const short* __restrict__ apack, const short* __restrict__ bpack,
    const int* __restrict__ im_len, const int* __restrict__ s_len,
    float* __restrict__ scores)
{
    __shared__ short As[12288];   // 2 windows x 12 chunks x 1 KB = 24 KB

    const int tid  = threadIdx.x;
    const int wave = tid >> 6;
    const int lane = tid & 63;
    const int q    = lane >> 4;
    const int l15  = lane & 15;
    const int b0   = blockIdx.x * 2;
    const int c0   = blockIdx.y * 8;

    // A staging map: slot s = r*256+tid covers chunk c=s>>6 lane l=s&63,
    // chunk c = kcl*6 + img*3 + mt  (window layout == apack order)
    const char* aSrc[3];
    int aDst[3];
    #pragma unroll
    for (int r = 0; r < 3; ++r) {
        int s = r * 256 + tid;
        int c = s >> 6, l = s & 63;
        int kcl = c / 6, rm = c - kcl * 6;
        int img = rm / 3, mt = rm - img * 3;
        aSrc[r] = (const char*)apack + (size_t)(b0 + img) * A_IMG_B
                + kcl * 3072 + mt * 1024 + l * 16;
        aDst[r] = s * 8;   // shorts
    }
    const char* bp[4];
    #pragma unroll
    for (int t = 0; t < 4; ++t)
        bp[t] = (const char*)bpack + (size_t)(c0 + 2 * wave + (t >> 1)) * B_SNT_B
              + (t & 1) * 1024 + lane * 16;

    f32x4 acc[6][4];
    #pragma unroll
    for (int f = 0; f < 6; ++f)
        #pragma unroll
        for (int t = 0; t < 4; ++t)
            acc[f][t] = (f32x4){0.f, 0.f, 0.f, 0.f};

    uint4 st[3];
    #pragma unroll
    for (int r = 0; r < 3; ++r) st[r] = *(const uint4*)aSrc[r];
    bf16x8 Bc[4], Bn[4];
    #pragma unroll
    for (int t = 0; t < 4; ++t) Bc[t] = *(const bf16x8*)bp[t];   // kc = 0

    for (int i = 0; i < 16; ++i) {
        const int bufs = (i & 1) * 6144;
        // write window i (data prefetched during iter i-1)
        #pragma unroll
        for (int r = 0; r < 3; ++r)
            *(uint4*)&As[bufs + aDst[r]] = st[r];
        // prefetch window i+1 A -> regs (stays in flight across barrier)
        if (i < 15) {
            #pragma unroll
            for (int r = 0; r < 3; ++r)
                st[r] = *(const uint4*)(aSrc[r] + (i + 1) * 6144);
        }
        // drain only LDS writes; global loads remain outstanding
        asm volatile("s_waitcnt lgkmcnt(0)\n\ts_barrier" ::: "memory");

        #pragma unroll
        for (int kcl = 0; kcl < 2; ++kcl) {
            const int kc = 2 * i + kcl;
            // prefetch B for kc+1 (final over-read lands in ws scores region)
            #pragma unroll
            for (int t = 0; t < 4; ++t)
                Bn[t] = *(const bf16x8*)(bp[t] + (kc + 1) * 2048);
            bf16x8 af[6];
            #pragma unroll
            for (int f = 0; f < 6; ++f)
                af[f] = *(const bf16x8*)&As[bufs + (kcl * 6 + f) * 512 + lane * 8];
            #pragma unroll
            for (int f = 0; f < 6; ++f)
                #pragma unroll
                for (int t = 0; t < 4; ++t)
                    acc[f][t] = __builtin_amdgcn_mfma_f32_16x16x32_bf16(
                        af[f], Bc[t], acc[f][t], 0, 0, 0);
            #pragma unroll
            for (int t = 0; t < 4; ++t) Bc[t] = Bn[t];
        }
    }

    // Fused epilogue. C/D layout: lane holds col = lane&15, row = (lane>>4)*4 + r.
    const int iml0 = im_len[b0] - 1;       // in [9, 36]
    const int iml1 = im_len[b0 + 1] - 1;

    float sc[2][2] = {{0.f, 0.f}, {0.f, 0.f}};
    #pragma unroll
    for (int t = 0; t < 4; ++t) {
        const int nt = wave * 4 + t;
        const int c  = c0 + (nt >> 1);
        const int sl = s_len[c] - 3;                 // valid words, in [5, 30]
        const int jj = (nt & 1) * 16 + l15;          // word index within sentence
        const bool jv = (jj < sl);
        #pragma unroll
        for (int bb = 0; bb < 2; ++bb) {
            const int il = bb ? iml1 : iml0;
            float m = -3.4e38f;
            #pragma unroll
            for (int mt3 = 0; mt3 < 3; ++mt3) {
                #pragma unroll
                for (int r = 0; r < 4; ++r) {
                    int i = mt3 * 16 + q * 4 + r;    // global region index
                    float v = acc[bb * 3 + mt3][t][r];
                    if (i < il) m = fmaxf(m, v);     // pads & masked rows excluded
                }
            }
            m = fmaxf(m, __shfl_xor(m, 16, 64));
            m = fmaxf(m, __shfl_xor(m, 32, 64));
            // reference: masked entries are 0 and join the max iff il < 36
            if (il < LI) m = fmaxf(m, 0.f);
            float v = (q == 0 && jv) ? m : 0.f;      // count each column once
            #pragma unroll
            for (int off = 32; off >= 1; off >>= 1) v += __shfl_xor(v, off, 64);
            sc[bb][t >> 1] += v;
        }
    }
    if (lane == 0) {
        #pragma unroll
        for (int bb = 0; bb < 2; ++bb)
            #pragma unroll
            for (int h = 0; h < 2; ++h)
                scores[(b0 + bb) * NB + c0 + wave * 2 + h] = sc[bb][h];
    }
}

// Block t: cost_s[t] = max_{c!=t} relu(M + s[t][c] - s[t][t]),
//          cost_im[t] = max_{b!=t} relu(M + s[b][t] - s[t][t]).
__global__ __launch_bounds__(256) void loss_part(
    const float* __restrict__ sc, float* __restrict__ part)
{
    const int t = blockIdx.x, k = threadIdx.x;
    const float dt = sc[t * (NB + 1)];
    float rv = 0.f, cv = 0.f;
    if (k != t) {
        rv = fmaxf(0.2f + sc[t * NB + k] - dt, 0.f);
        cv = fmaxf(0.2f + sc[k * NB + t] - dt, 0.f);
    }
    #pragma unroll
    for (int o = 32; o >= 1; o >>= 1) {
        rv = fmaxf(rv, __shfl_xor(rv, o, 64));
        cv = fmaxf(cv, __shfl_xor(cv, o, 64));
    }
    __shared__ float rr[4], cc[4];
    if ((k & 63) == 0) { rr[k >> 6] = rv; cc[k >> 6] = cv; }
    __syncthreads();
    if (k == 0) {
        float rm = fmaxf(fmaxf(rr[0], rr[1]), fmaxf(rr[2], rr[3]));
        float cm = fmaxf(fmaxf(cc[0], cc[1]), fmaxf(cc[2], cc[3]));
        part[t] = rm + cm;
    }
}

__global__ __launch_bounds__(256) void loss_final(
    const float* __restrict__ part, float* __restrict__ out)
{
    float v = part[threadIdx.x];
    __shared__ float red[4];
    #pragma unroll
    for (int o = 32; o >= 1; o >>= 1) v += __shfl_xor(v, o, 64);
    if ((threadIdx.x & 63) == 0) red[threadIdx.x >> 6] = v;
    __syncthreads();
    if (threadIdx.x == 0) out[0] = red[0] + red[1] + red[2] + red[3];
}

extern "C" void kernel_launch(void* const* d_in, const int* in_sizes, int n_in,
                              void* d_out, int out_size, void* d_ws, size_t ws_size,
                              hipStream_t stream) {
    const float* im_set = (const float*)d_in[0];
    const float* s_seq  = (const float*)d_in[1];
    const int*   im_len = (const int*)d_in[2];
    const int*   s_len  = (const int*)d_in[3];
    float* out = (float*)d_out;

    char* ws = (char*)d_ws;
    const size_t apack_bytes = (size_t)NB * A_IMG_B;   // 25.2 MB
    const size_t bpack_bytes = (size_t)NB * B_SNT_B;   // 16.8 MB
    short* apack  = (short*)ws;
    short* bpack  = (short*)(ws + apack_bytes);
    float* scores = (float*)(ws + apack_bytes + bpack_bytes);  // 256 KB
    float* part   = scores + NB * NB;                          // 1 KB
    // (final-iteration dead B prefetch over-reads <= 2 KB past bpack end,
    //  landing in the scores region of this same ws allocation -> safe)

    norm_pack<<<512, 256, 0, stream>>>(im_set, s_seq, apack, bpack);

    dim3 grid(NB / 2, NB / 8);
    gemm_scores<<<grid, 256, 0, stream>>>(apack, bpack, im_len, s_len, scores);

    loss_part<<<NB, 256, 0, stream>>>(scores, part);
    loss_final<<<1, 256, 0, stream>>>(part, out);
}